// Round 1
// 567.609 us; speedup vs baseline: 1.0281x; 1.0281x over previous
//
#include <hip/hip_runtime.h>

// Node2Edge2Node GNN block, MI355X (gfx950) — R4: atomic-free CSR build.
//
//   agg[v] = (Σ_{e->v} x[src_e]) @ W1a  +  cnt_v * (x[v] @ W1b)
//          + (Σ_{e->v} ea_e)    @ W1c  +  cnt_v * b1
//   out    = [agg | x] @ W2 + b2
//
// R4 theory: the 1.28M scattered device-scope atomics in the old
// k_hist/k_fill resolve at the cross-XCD fabric (8 non-coherent L2s) and
// were the dominant cost (~400 us by arithmetic). CSR is now built with
// ZERO global atomics:
//   k_prep (xb cast + weight pack)
//   k_hist   : 64 blocks x 10000-edge chunks; full 40KB LDS histogram
//              (LDS atomics only), flushed with plain coalesced stores.
//   k_colscan: per-node exclusive prefix across the 64 block-partials
//              (in-place) + counts.
//   k_scan   : global exclusive scan -> row_ptr.
//   k_fill   : blocks re-read their own chunk; intra-block rank via LDS
//              fetch-add; pos = row_ptr[d] + hist[b][d] + rank. Plain writes.
//   k_sum, k_out: UNCHANGED from R3 (delta attribution).

#define NN 10000
#define ED 640000
#define D  128
#define NB 64                 // histogram blocks
#define EPB (ED / NB)         // 10000 edges per block (exact)

typedef __bf16 bf16;
typedef bf16  bf16x8 __attribute__((ext_vector_type(8)));
typedef float f32x4  __attribute__((ext_vector_type(4)));

__device__ __forceinline__ bf16 f2b(float f) {
  unsigned u = __builtin_bit_cast(unsigned, f);
  u += 0x7fffu + ((u >> 16) & 1u);               // RTNE
  unsigned short h = (unsigned short)(u >> 16);
  return __builtin_bit_cast(bf16, h);
}

__device__ __forceinline__ bf16x8 bzero8() {
  bf16 z = __builtin_bit_cast(bf16, (unsigned short)0);
  bf16x8 v = {z, z, z, z, z, z, z, z};
  return v;
}

// ---------------------------------------------------------------------------
// K1: x -> bf16; pack W1 (384x128) and W2 (256x128) into MFMA B-frag layout:
// Bp[((kb*8 + t)*64 + L)*8 + j] = W[kb*32 + (L>>4)*8 + j][t*16 + (L&15)]
// ---------------------------------------------------------------------------
__global__ __launch_bounds__(256) void k_prep(const float* __restrict__ x,
                                              const float* __restrict__ W1,
                                              const float* __restrict__ W2,
                                              bf16* __restrict__ xb,
                                              bf16* __restrict__ W1p,
                                              bf16* __restrict__ W2p) {
  int id = blockIdx.x * 256 + threadIdx.x;
  if (id < 160000) {                    // xb: 10000*128/8 chunks
    int i = id * 8;
    f32x4 a = *(const f32x4*)(x + i);
    f32x4 b = *(const f32x4*)(x + i + 4);
    bf16x8 h;
    h[0]=f2b(a[0]); h[1]=f2b(a[1]); h[2]=f2b(a[2]); h[3]=f2b(a[3]);
    h[4]=f2b(b[0]); h[5]=f2b(b[1]); h[6]=f2b(b[2]); h[7]=f2b(b[3]);
    *(bf16x8*)(xb + i) = h;
  } else if (id < 166144) {             // W1p: kb 0..11 (K=384)
    int o8 = id - 160000;
    int kb = o8 >> 9, rem = o8 & 511, t = rem >> 6, L = rem & 63;
    int col  = t * 16 + (L & 15);
    int row0 = kb * 32 + (L >> 4) * 8;
    bf16x8 h;
    #pragma unroll
    for (int j = 0; j < 8; j++) h[j] = f2b(W1[(row0 + j) * D + col]);
    *(bf16x8*)(W1p + o8 * 8) = h;
  } else if (id < 170240) {             // W2p: kb 0..7 (K=256)
    int o8 = id - 166144;
    int kb = o8 >> 9, rem = o8 & 511, t = rem >> 6, L = rem & 63;
    int col  = t * 16 + (L & 15);
    int row0 = kb * 32 + (L >> 4) * 8;
    bf16x8 h;
    #pragma unroll
    for (int j = 0; j < 8; j++) h[j] = f2b(W2[(row0 + j) * D + col]);
    *(bf16x8*)(W2p + o8 * 8) = h;
  }
}

// ---------------------------------------------------------------------------
// K2: per-chunk histograms. Block b owns edges [b*EPB, (b+1)*EPB).
// Full node-range histogram in LDS (40 KB); LDS atomics only; plain flush.
// ---------------------------------------------------------------------------
__global__ __launch_bounds__(256) void k_hist(const int* __restrict__ dst,
                                              int* __restrict__ hist) {
  __shared__ int h[NN];
  int b = blockIdx.x, tid = threadIdx.x;
  for (int i = tid; i < NN; i += 256) h[i] = 0;
  __syncthreads();
  int base = b * EPB;
  for (int i = tid; i < EPB; i += 256) atomicAdd(&h[dst[base + i]], 1);
  __syncthreads();
  int* outp = hist + (size_t)b * NN;
  for (int i = tid; i < NN; i += 256) outp[i] = h[i];
}

// ---------------------------------------------------------------------------
// K3: per-node exclusive prefix over the NB block-partials (in place),
// total into counts. Coalesced across v; NB sequential steps.
// ---------------------------------------------------------------------------
__global__ __launch_bounds__(256) void k_colscan(int* __restrict__ hist,
                                                 int* __restrict__ counts) {
  int v = blockIdx.x * 256 + threadIdx.x;
  if (v >= NN) return;
  int run = 0;
  #pragma unroll
  for (int b = 0; b < NB; b++) {
    int t = hist[b * NN + v];
    hist[b * NN + v] = run;
    run += t;
  }
  counts[v] = run;
}

// K4: single-block exclusive scan -> row_ptr
__global__ __launch_bounds__(256) void k_scan(const int* __restrict__ counts,
                                              int* __restrict__ row_ptr) {
  __shared__ int part[256];
  int tid = threadIdx.x;
  const int CH = 40;                    // 256*40 = 10240 >= NN
  int base = tid * CH;
  int sum = 0;
  for (int i = 0; i < CH; i++) { int idx = base + i; if (idx < NN) sum += counts[idx]; }
  part[tid] = sum;
  __syncthreads();
  for (int off = 1; off < 256; off <<= 1) {
    int v = (tid >= off) ? part[tid - off] : 0;
    __syncthreads();
    part[tid] += v;
    __syncthreads();
  }
  int run = part[tid] - sum;            // exclusive prefix
  for (int i = 0; i < CH; i++) {
    int idx = base + i;
    if (idx < NN) { row_ptr[idx] = run; run += counts[idx]; }
  }
  if (tid == 255) row_ptr[NN] = part[255];
}

// ---------------------------------------------------------------------------
// K5: scatter edges into CSR order with NO global atomics.
// pos = row_ptr[d] + hist[b][d] (cross-block exclusive prefix for this node)
//     + rank (intra-block rank via LDS fetch-add). Bijective per segment;
// intra-segment order is irrelevant (commutative sum downstream).
// ---------------------------------------------------------------------------
__global__ __launch_bounds__(256) void k_fill(const int* __restrict__ src,
                                              const int* __restrict__ dst,
                                              const int* __restrict__ row_ptr,
                                              const int* __restrict__ hist,
                                              int2* __restrict__ csr) {
  __shared__ int rk[NN];
  int b = blockIdx.x, tid = threadIdx.x;
  for (int i = tid; i < NN; i += 256) rk[i] = 0;
  __syncthreads();
  int base = b * EPB;
  const int* __restrict__ hb = hist + (size_t)b * NN;
  for (int i = tid; i < EPB; i += 256) {
    int e = base + i;
    int d = dst[e];
    int r = atomicAdd(&rk[d], 1);       // LDS fetch-add: cheap
    int pos = row_ptr[d] + hb[d] + r;
    csr[pos] = make_int2(e, src[e]);
  }
}

// ---------------------------------------------------------------------------
// K6 (UNCHANGED): per-node segment sums. sx[v] = Σ x[src_e], sea[v] = Σ ea_e.
// One wave per node. Lane = g*16 + l: group g handles edges e0+g, e0+g+4, ...
// lane covers cols [8l, 8l+8). ea: the 327 MB HBM stream. xb: L2-resident.
// ---------------------------------------------------------------------------
__global__ __launch_bounds__(256) void k_sum(const bf16*  __restrict__ xb,
                                             const float* __restrict__ ea,
                                             const int*   __restrict__ row_ptr,
                                             const int2*  __restrict__ csr,
                                             float* __restrict__ sx,
                                             float* __restrict__ sea) {
  int gwave = (blockIdx.x * 256 + threadIdx.x) >> 6;   // 0..9999
  if (gwave >= NN) return;
  int lane = threadIdx.x & 63;
  int g = lane >> 4, l = lane & 15;
  int e0 = row_ptr[gwave], e1 = row_ptr[gwave + 1];

  f32x4 ax0 = {0.f,0.f,0.f,0.f}, ax1 = {0.f,0.f,0.f,0.f};
  f32x4 ae0 = {0.f,0.f,0.f,0.f}, ae1 = {0.f,0.f,0.f,0.f};

  #pragma unroll 2
  for (int e = e0 + g; e < e1; e += 4) {
    int2 es = csr[e];
    bf16x8 hx = *(const bf16x8*)(xb + (size_t)es.y * D + l * 8);
    const float* ep = ea + (size_t)es.x * D + l * 8;
    f32x4 f0 = *(const f32x4*)ep;
    f32x4 f1 = *(const f32x4*)(ep + 4);
    ax0[0] += (float)hx[0]; ax0[1] += (float)hx[1];
    ax0[2] += (float)hx[2]; ax0[3] += (float)hx[3];
    ax1[0] += (float)hx[4]; ax1[1] += (float)hx[5];
    ax1[2] += (float)hx[6]; ax1[3] += (float)hx[7];
    ae0 += f0;
    ae1 += f1;
  }
  // reduce across the 4 groups (lane bits 4,5)
  #pragma unroll
  for (int i = 0; i < 4; i++) {
    ax0[i] += __shfl_xor(ax0[i], 16, 64); ax0[i] += __shfl_xor(ax0[i], 32, 64);
    ax1[i] += __shfl_xor(ax1[i], 16, 64); ax1[i] += __shfl_xor(ax1[i], 32, 64);
    ae0[i] += __shfl_xor(ae0[i], 16, 64); ae0[i] += __shfl_xor(ae0[i], 32, 64);
    ae1[i] += __shfl_xor(ae1[i], 16, 64); ae1[i] += __shfl_xor(ae1[i], 32, 64);
  }
  if (lane < 16) {
    float* px = sx  + (size_t)gwave * D + l * 8;
    float* pe = sea + (size_t)gwave * D + l * 8;
    *(f32x4*)px       = ax0;
    *(f32x4*)(px + 4) = ax1;
    *(f32x4*)pe       = ae0;
    *(f32x4*)(pe + 4) = ae1;
  }
}

// ---------------------------------------------------------------------------
// K7 (UNCHANGED): fused per-node GEMMs.  64 nodes/block, 157 blocks.
//   stage1: agg = [sx | cnt*x | sea] @ W1 + cnt*b1          (K=384)
//   stage2: out = [bf16(agg) | xb] @ W2 + b2                (K=256)
// ---------------------------------------------------------------------------
__global__ __launch_bounds__(256) void k_out(const float* __restrict__ sx,
                                             const float* __restrict__ sea,
                                             const bf16*  __restrict__ xb,
                                             const bf16*  __restrict__ W1p,
                                             const bf16*  __restrict__ W2p,
                                             const float* __restrict__ b1,
                                             const float* __restrict__ b2,
                                             const int*   __restrict__ row_ptr,
                                             float* __restrict__ out) {
  __shared__ __align__(16) bf16 lds[64 * 392];   // 50.2 KB
  int tid  = threadIdx.x;
  int wave = tid >> 6, lane = tid & 63, quad = lane >> 4, l16 = lane & 15;
  int n0 = blockIdx.x * 64;

  // ---- stage-1 staging: A1[m][*] = [sx | cnt*x | sea] bf16, stride 392
  #pragma unroll
  for (int i = 0; i < 4; i++) {
    int m = (tid >> 4) + 16 * i;
    int v = n0 + m;
    int cl = tid & 15;
    float cntf = (v < NN) ? (float)(row_ptr[v + 1] - row_ptr[v]) : 0.f;
    #pragma unroll
    for (int j = 0; j < 3; j++) {
      int c = cl + 16 * j;              // chunk 0..47
      bf16x8 h;
      if (v < NN) {
        if (j == 0) {
          const float* p = sx + (size_t)v * D + cl * 8;
          f32x4 f0 = *(const f32x4*)p, f1 = *(const f32x4*)(p + 4);
          h[0]=f2b(f0[0]); h[1]=f2b(f0[1]); h[2]=f2b(f0[2]); h[3]=f2b(f0[3]);
          h[4]=f2b(f1[0]); h[5]=f2b(f1[1]); h[6]=f2b(f1[2]); h[7]=f2b(f1[3]);
        } else if (j == 1) {
          bf16x8 hx = *(const bf16x8*)(xb + (size_t)v * D + cl * 8);
          #pragma unroll
          for (int k = 0; k < 8; k++) h[k] = f2b((float)hx[k] * cntf);
        } else {
          const float* p = sea + (size_t)v * D + cl * 8;
          f32x4 f0 = *(const f32x4*)p, f1 = *(const f32x4*)(p + 4);
          h[0]=f2b(f0[0]); h[1]=f2b(f0[1]); h[2]=f2b(f0[2]); h[3]=f2b(f0[3]);
          h[4]=f2b(f1[0]); h[5]=f2b(f1[1]); h[6]=f2b(f1[2]); h[7]=f2b(f1[3]);
        }
      } else h = bzero8();
      *(bf16x8*)&lds[m * 392 + c * 8] = h;
    }
  }
  __syncthreads();

  // ---- stage-1 GEMM (K=384)
  f32x4 acc[4][2];
  #pragma unroll
  for (int mt = 0; mt < 4; mt++)
    #pragma unroll
    for (int tt = 0; tt < 2; tt++) acc[mt][tt] = (f32x4){0.f, 0.f, 0.f, 0.f};

  #pragma unroll
  for (int kb = 0; kb < 12; kb++) {
    bf16x8 B0 = *(const bf16x8*)(W1p + ((kb * 8 + wave * 2 + 0) * 64 + lane) * 8);
    bf16x8 B1 = *(const bf16x8*)(W1p + ((kb * 8 + wave * 2 + 1) * 64 + lane) * 8);
    #pragma unroll
    for (int mt = 0; mt < 4; mt++) {
      bf16x8 a = *(const bf16x8*)&lds[(mt * 16 + l16) * 392 + kb * 32 + quad * 8];
      acc[mt][0] = __builtin_amdgcn_mfma_f32_16x16x32_bf16(a, B0, acc[mt][0], 0, 0, 0);
      acc[mt][1] = __builtin_amdgcn_mfma_f32_16x16x32_bf16(a, B1, acc[mt][1], 0, 0, 0);
    }
  }
  __syncthreads();                      // all A1 reads done; lds reused as A2

  // ---- epilogue-1: agg = acc + cnt*b1 -> bf16 into A2 cols [0,128), stride 264
  #pragma unroll
  for (int tt = 0; tt < 2; tt++) {
    int col = wave * 32 + tt * 16 + l16;
    float bb = b1[col];
    #pragma unroll
    for (int mt = 0; mt < 4; mt++)
      #pragma unroll
      for (int r = 0; r < 4; r++) {
        int m = mt * 16 + quad * 4 + r;
        int v = n0 + m;
        float cntf = (v < NN) ? (float)(row_ptr[v + 1] - row_ptr[v]) : 0.f;
        lds[m * 264 + col] = f2b(acc[mt][tt][r] + cntf * bb);
      }
  }
  // ---- A2 cols [128,256) = xb
  #pragma unroll
  for (int i = 0; i < 4; i++) {
    int m = (tid >> 4) + 16 * i;
    int c = tid & 15;
    int v = n0 + m;
    bf16x8 h = (v < NN) ? *(const bf16x8*)(xb + (size_t)v * D + c * 8) : bzero8();
    *(bf16x8*)&lds[m * 264 + 128 + c * 8] = h;
  }
  __syncthreads();

  // ---- stage-2 GEMM (K=256)
  f32x4 acc2[4][2];
  #pragma unroll
  for (int mt = 0; mt < 4; mt++)
    #pragma unroll
    for (int tt = 0; tt < 2; tt++) acc2[mt][tt] = (f32x4){0.f, 0.f, 0.f, 0.f};

  #pragma unroll
  for (int kb = 0; kb < 8; kb++) {
    bf16x8 B0 = *(const bf16x8*)(W2p + ((kb * 8 + wave * 2 + 0) * 64 + lane) * 8);
    bf16x8 B1 = *(const bf16x8*)(W2p + ((kb * 8 + wave * 2 + 1) * 64 + lane) * 8);
    #pragma unroll
    for (int mt = 0; mt < 4; mt++) {
      bf16x8 a = *(const bf16x8*)&lds[(mt * 16 + l16) * 264 + kb * 32 + quad * 8];
      acc2[mt][0] = __builtin_amdgcn_mfma_f32_16x16x32_bf16(a, B0, acc2[mt][0], 0, 0, 0);
      acc2[mt][1] = __builtin_amdgcn_mfma_f32_16x16x32_bf16(a, B1, acc2[mt][1], 0, 0, 0);
    }
  }

  #pragma unroll
  for (int tt = 0; tt < 2; tt++) {
    int col = wave * 32 + tt * 16 + l16;
    float bb = b2[col];
    #pragma unroll
    for (int mt = 0; mt < 4; mt++)
      #pragma unroll
      for (int r = 0; r < 4; r++) {
        int v = n0 + mt * 16 + quad * 4 + r;
        if (v < NN) out[(size_t)v * D + col] = acc2[mt][tt][r] + bb;
      }
  }
}

// ---------------------------------------------------------------------------
extern "C" void kernel_launch(void* const* d_in, const int* in_sizes, int n_in,
                              void* d_out, int out_size, void* d_ws, size_t ws_size,
                              hipStream_t stream) {
  const float* x  = (const float*)d_in[0];
  const int*   ei = (const int*)  d_in[1];   // [2, E]: src = ei, dst = ei + ED
  const float* ea = (const float*)d_in[2];
  const float* W1 = (const float*)d_in[3];
  const float* b1 = (const float*)d_in[4];
  const float* W2 = (const float*)d_in[5];
  const float* b2 = (const float*)d_in[6];
  float* out = (float*)d_out;

  char* ws = (char*)d_ws;
  size_t off = 0;
  auto alloc = [&](size_t bytes) -> void* {
    void* p = ws + off;
    off += (bytes + 255) & ~(size_t)255;
    return p;
  };
  bf16*  xb      = (bf16*)alloc((size_t)NN * D * 2);
  bf16*  W1p     = (bf16*)alloc(49152 * 2);       // 384*128
  bf16*  W2p     = (bf16*)alloc(32768 * 2);       // 256*128
  float* sx      = (float*)alloc((size_t)NN * D * 4);
  float* sea     = (float*)alloc((size_t)NN * D * 4);
  int*   counts  = (int*)alloc(NN * 4);
  int*   row_ptr = (int*)alloc((NN + 1) * 4);
  int*   hist    = (int*)alloc((size_t)NB * NN * 4);   // 2.56 MB block-partials
  int2*  csr     = (int2*)alloc((size_t)ED * 8);
  (void)ws_size; (void)in_sizes; (void)n_in; (void)out_size;  // ~21 MB

  const int* src = ei;
  const int* dst = ei + ED;

  k_prep<<<665, 256, 0, stream>>>(x, W1, W2, xb, W1p, W2p);
  k_hist<<<NB, 256, 0, stream>>>(dst, hist);
  k_colscan<<<40, 256, 0, stream>>>(hist, counts);
  k_scan<<<1, 256, 0, stream>>>(counts, row_ptr);
  k_fill<<<NB, 256, 0, stream>>>(src, dst, row_ptr, hist, csr);
  k_sum<<<2500, 256, 0, stream>>>(xb, ea, row_ptr, csr, sx, sea);
  k_out<<<157, 256, 0, stream>>>(sx, sea, xb, W1p, W2p, b1, b2, row_ptr, out);
}

// Round 2
// 519.660 us; speedup vs baseline: 1.1229x; 1.0923x over previous
//
#include <hip/hip_runtime.h>

// Node2Edge2Node GNN block, MI355X (gfx950) — R5: cache-steered k_sum.
//
//   agg[v] = (Σ_{e->v} x[src_e]) @ W1a  +  cnt_v * (x[v] @ W1b)
//          + (Σ_{e->v} ea_e)    @ W1c  +  cnt_v * b1
//   out    = [agg | x] @ W2 + b2
//
// R5 theory: ~394 us of dur is harness workspace poison (2x 1.31GB fills /
// iter, untouchable); controllable budget ~170 us is dominated by k_sum's
// 327MB random ea gather + 164MB xb gather. ea (read-once) thrashes L2 and
// evicts xb. Fix: non-temporal loads for ea/csr so xb stays L2-resident.
// Plus int4 vectorization of the CSR-build chain. No numeric changes.

#define NN 10000
#define ED 640000
#define D  128
#define NB 64                 // histogram blocks
#define EPB (ED / NB)         // 10000 edges per block (exact)

typedef __bf16 bf16;
typedef bf16  bf16x8 __attribute__((ext_vector_type(8)));
typedef float f32x4  __attribute__((ext_vector_type(4)));

__device__ __forceinline__ bf16 f2b(float f) {
  unsigned u = __builtin_bit_cast(unsigned, f);
  u += 0x7fffu + ((u >> 16) & 1u);               // RTNE
  unsigned short h = (unsigned short)(u >> 16);
  return __builtin_bit_cast(bf16, h);
}

__device__ __forceinline__ bf16x8 bzero8() {
  bf16 z = __builtin_bit_cast(bf16, (unsigned short)0);
  bf16x8 v = {z, z, z, z, z, z, z, z};
  return v;
}

// ---------------------------------------------------------------------------
// K1: x -> bf16; pack W1 (384x128) and W2 (256x128) into MFMA B-frag layout:
// Bp[((kb*8 + t)*64 + L)*8 + j] = W[kb*32 + (L>>4)*8 + j][t*16 + (L&15)]
// ---------------------------------------------------------------------------
__global__ __launch_bounds__(256) void k_prep(const float* __restrict__ x,
                                              const float* __restrict__ W1,
                                              const float* __restrict__ W2,
                                              bf16* __restrict__ xb,
                                              bf16* __restrict__ W1p,
                                              bf16* __restrict__ W2p) {
  int id = blockIdx.x * 256 + threadIdx.x;
  if (id < 160000) {                    // xb: 10000*128/8 chunks
    int i = id * 8;
    f32x4 a = *(const f32x4*)(x + i);
    f32x4 b = *(const f32x4*)(x + i + 4);
    bf16x8 h;
    h[0]=f2b(a[0]); h[1]=f2b(a[1]); h[2]=f2b(a[2]); h[3]=f2b(a[3]);
    h[4]=f2b(b[0]); h[5]=f2b(b[1]); h[6]=f2b(b[2]); h[7]=f2b(b[3]);
    *(bf16x8*)(xb + i) = h;
  } else if (id < 166144) {             // W1p: kb 0..11 (K=384)
    int o8 = id - 160000;
    int kb = o8 >> 9, rem = o8 & 511, t = rem >> 6, L = rem & 63;
    int col  = t * 16 + (L & 15);
    int row0 = kb * 32 + (L >> 4) * 8;
    bf16x8 h;
    #pragma unroll
    for (int j = 0; j < 8; j++) h[j] = f2b(W1[(row0 + j) * D + col]);
    *(bf16x8*)(W1p + o8 * 8) = h;
  } else if (id < 170240) {             // W2p: kb 0..7 (K=256)
    int o8 = id - 166144;
    int kb = o8 >> 9, rem = o8 & 511, t = rem >> 6, L = rem & 63;
    int col  = t * 16 + (L & 15);
    int row0 = kb * 32 + (L >> 4) * 8;
    bf16x8 h;
    #pragma unroll
    for (int j = 0; j < 8; j++) h[j] = f2b(W2[(row0 + j) * D + col]);
    *(bf16x8*)(W2p + o8 * 8) = h;
  }
}

// ---------------------------------------------------------------------------
// K2: per-chunk histograms. Block b owns edges [b*EPB, (b+1)*EPB).
// Full node-range histogram in LDS (40 KB); LDS atomics only; int4 I/O.
// ---------------------------------------------------------------------------
__global__ __launch_bounds__(256) void k_hist(const int* __restrict__ dst,
                                              int* __restrict__ hist) {
  __shared__ __align__(16) int h[NN];
  int b = blockIdx.x, tid = threadIdx.x;
  int4 z4 = make_int4(0, 0, 0, 0);
  for (int i = tid; i < NN / 4; i += 256) ((int4*)h)[i] = z4;
  __syncthreads();
  const int4* d4 = (const int4*)(dst + b * EPB);
  for (int i = tid; i < EPB / 4; i += 256) {
    int4 dd = d4[i];
    atomicAdd(&h[dd.x], 1);
    atomicAdd(&h[dd.y], 1);
    atomicAdd(&h[dd.z], 1);
    atomicAdd(&h[dd.w], 1);
  }
  __syncthreads();
  int4* outp = (int4*)(hist + (size_t)b * NN);
  for (int i = tid; i < NN / 4; i += 256) outp[i] = ((const int4*)h)[i];
}

// ---------------------------------------------------------------------------
// K3: per-node exclusive prefix over the NB block-partials (in place),
// total into counts. Coalesced across v; NB sequential steps.
// ---------------------------------------------------------------------------
__global__ __launch_bounds__(256) void k_colscan(int* __restrict__ hist,
                                                 int* __restrict__ counts) {
  int v = blockIdx.x * 256 + threadIdx.x;
  if (v >= NN) return;
  int run = 0;
  #pragma unroll
  for (int b = 0; b < NB; b++) {
    int t = hist[b * NN + v];
    hist[b * NN + v] = run;
    run += t;
  }
  counts[v] = run;
}

// K4: single-block exclusive scan -> row_ptr (register-blocked, int4 I/O)
__global__ __launch_bounds__(256) void k_scan(const int* __restrict__ counts,
                                              int* __restrict__ row_ptr) {
  __shared__ int part[256];
  int tid = threadIdx.x;
  const int CH = 40;                    // 256*40 = 10240 >= NN
  int base = tid * CH;
  int loc[CH];
  if (base + CH <= NN) {
    #pragma unroll
    for (int i = 0; i < CH / 4; i++) {
      int4 t = *(const int4*)(counts + base + i * 4);
      loc[i*4] = t.x; loc[i*4+1] = t.y; loc[i*4+2] = t.z; loc[i*4+3] = t.w;
    }
  } else {
    #pragma unroll
    for (int i = 0; i < CH; i++) loc[i] = (base + i < NN) ? counts[base + i] : 0;
  }
  int sum = 0;
  #pragma unroll
  for (int i = 0; i < CH; i++) sum += loc[i];
  part[tid] = sum;
  __syncthreads();
  for (int off = 1; off < 256; off <<= 1) {
    int v = (tid >= off) ? part[tid - off] : 0;
    __syncthreads();
    part[tid] += v;
    __syncthreads();
  }
  int run = part[tid] - sum;            // exclusive prefix
  if (base + CH <= NN) {
    #pragma unroll
    for (int i = 0; i < CH / 4; i++) {
      int4 t;
      t.x = run; run += loc[i*4];
      t.y = run; run += loc[i*4+1];
      t.z = run; run += loc[i*4+2];
      t.w = run; run += loc[i*4+3];
      *(int4*)(row_ptr + base + i * 4) = t;
    }
  } else {
    #pragma unroll
    for (int i = 0; i < CH; i++) {
      int idx = base + i;
      if (idx < NN) { row_ptr[idx] = run; run += loc[i]; }
    }
  }
  if (tid == 255) row_ptr[NN] = part[255];
}

// ---------------------------------------------------------------------------
// K5: scatter edges into CSR order with NO global atomics.
// pos = row_ptr[d] + hist[b][d] (cross-block exclusive prefix for this node)
//     + rank (intra-block rank via LDS fetch-add). Bijective per segment.
// ---------------------------------------------------------------------------
__global__ __launch_bounds__(256) void k_fill(const int* __restrict__ src,
                                              const int* __restrict__ dst,
                                              const int* __restrict__ row_ptr,
                                              const int* __restrict__ hist,
                                              int2* __restrict__ csr) {
  __shared__ __align__(16) int rk[NN];
  int b = blockIdx.x, tid = threadIdx.x;
  int4 z4 = make_int4(0, 0, 0, 0);
  for (int i = tid; i < NN / 4; i += 256) ((int4*)rk)[i] = z4;
  __syncthreads();
  int base = b * EPB;
  const int* __restrict__ hb = hist + (size_t)b * NN;
  const int4* d4 = (const int4*)(dst + base);
  const int4* s4 = (const int4*)(src + base);
  for (int i = tid; i < EPB / 4; i += 256) {
    int4 dd = d4[i];
    int4 ss = s4[i];
    int e = base + i * 4;
    {
      int r = atomicAdd(&rk[dd.x], 1);
      csr[row_ptr[dd.x] + hb[dd.x] + r] = make_int2(e + 0, ss.x);
    }
    {
      int r = atomicAdd(&rk[dd.y], 1);
      csr[row_ptr[dd.y] + hb[dd.y] + r] = make_int2(e + 1, ss.y);
    }
    {
      int r = atomicAdd(&rk[dd.z], 1);
      csr[row_ptr[dd.z] + hb[dd.z] + r] = make_int2(e + 2, ss.z);
    }
    {
      int r = atomicAdd(&rk[dd.w], 1);
      csr[row_ptr[dd.w] + hb[dd.w] + r] = make_int2(e + 3, ss.w);
    }
  }
}

// ---------------------------------------------------------------------------
// K6: per-node segment sums. sx[v] = Σ x[src_e], sea[v] = Σ ea_e.
// One wave per node; group g (of 4) handles edges e0+g, e0+g+4, ...; lane
// covers cols [8l, 8l+8). ea/csr are read-once: NON-TEMPORAL loads so the
// 327MB ea stream doesn't evict the L2-resident xb (2.5MB, gathered 164MB).
// ---------------------------------------------------------------------------
__global__ __launch_bounds__(256) void k_sum(const bf16*  __restrict__ xb,
                                             const float* __restrict__ ea,
                                             const int*   __restrict__ row_ptr,
                                             const int2*  __restrict__ csr,
                                             float* __restrict__ sx,
                                             float* __restrict__ sea) {
  int gwave = (blockIdx.x * 256 + threadIdx.x) >> 6;   // 0..9999
  if (gwave >= NN) return;
  int lane = threadIdx.x & 63;
  int g = lane >> 4, l = lane & 15;
  int e0 = row_ptr[gwave], e1 = row_ptr[gwave + 1];

  f32x4 ax0 = {0.f,0.f,0.f,0.f}, ax1 = {0.f,0.f,0.f,0.f};
  f32x4 ae0 = {0.f,0.f,0.f,0.f}, ae1 = {0.f,0.f,0.f,0.f};

  #pragma unroll 2
  for (int e = e0 + g; e < e1; e += 4) {
    long long cp = __builtin_nontemporal_load((const long long*)(csr + e));
    int2 es = __builtin_bit_cast(int2, cp);
    const f32x4* ep = (const f32x4*)(ea + (size_t)es.x * D + l * 8);
    f32x4 f0 = __builtin_nontemporal_load(ep);
    f32x4 f1 = __builtin_nontemporal_load(ep + 1);
    bf16x8 hx = *(const bf16x8*)(xb + (size_t)es.y * D + l * 8);
    ax0[0] += (float)hx[0]; ax0[1] += (float)hx[1];
    ax0[2] += (float)hx[2]; ax0[3] += (float)hx[3];
    ax1[0] += (float)hx[4]; ax1[1] += (float)hx[5];
    ax1[2] += (float)hx[6]; ax1[3] += (float)hx[7];
    ae0 += f0;
    ae1 += f1;
  }
  // reduce across the 4 groups (lane bits 4,5)
  #pragma unroll
  for (int i = 0; i < 4; i++) {
    ax0[i] += __shfl_xor(ax0[i], 16, 64); ax0[i] += __shfl_xor(ax0[i], 32, 64);
    ax1[i] += __shfl_xor(ax1[i], 16, 64); ax1[i] += __shfl_xor(ax1[i], 32, 64);
    ae0[i] += __shfl_xor(ae0[i], 16, 64); ae0[i] += __shfl_xor(ae0[i], 32, 64);
    ae1[i] += __shfl_xor(ae1[i], 16, 64); ae1[i] += __shfl_xor(ae1[i], 32, 64);
  }
  if (lane < 16) {
    float* px = sx  + (size_t)gwave * D + l * 8;
    float* pe = sea + (size_t)gwave * D + l * 8;
    *(f32x4*)px       = ax0;
    *(f32x4*)(px + 4) = ax1;
    *(f32x4*)pe       = ae0;
    *(f32x4*)(pe + 4) = ae1;
  }
}

// ---------------------------------------------------------------------------
// K7 (UNCHANGED): fused per-node GEMMs.  64 nodes/block, 157 blocks.
//   stage1: agg = [sx | cnt*x | sea] @ W1 + cnt*b1          (K=384)
//   stage2: out = [bf16(agg) | xb] @ W2 + b2                (K=256)
// ---------------------------------------------------------------------------
__global__ __launch_bounds__(256) void k_out(const float* __restrict__ sx,
                                             const float* __restrict__ sea,
                                             const bf16*  __restrict__ xb,
                                             const bf16*  __restrict__ W1p,
                                             const bf16*  __restrict__ W2p,
                                             const float* __restrict__ b1,
                                             const float* __restrict__ b2,
                                             const int*   __restrict__ row_ptr,
                                             float* __restrict__ out) {
  __shared__ __align__(16) bf16 lds[64 * 392];   // 50.2 KB
  int tid  = threadIdx.x;
  int wave = tid >> 6, lane = tid & 63, quad = lane >> 4, l16 = lane & 15;
  int n0 = blockIdx.x * 64;

  // ---- stage-1 staging: A1[m][*] = [sx | cnt*x | sea] bf16, stride 392
  #pragma unroll
  for (int i = 0; i < 4; i++) {
    int m = (tid >> 4) + 16 * i;
    int v = n0 + m;
    int cl = tid & 15;
    float cntf = (v < NN) ? (float)(row_ptr[v + 1] - row_ptr[v]) : 0.f;
    #pragma unroll
    for (int j = 0; j < 3; j++) {
      int c = cl + 16 * j;              // chunk 0..47
      bf16x8 h;
      if (v < NN) {
        if (j == 0) {
          const float* p = sx + (size_t)v * D + cl * 8;
          f32x4 f0 = *(const f32x4*)p, f1 = *(const f32x4*)(p + 4);
          h[0]=f2b(f0[0]); h[1]=f2b(f0[1]); h[2]=f2b(f0[2]); h[3]=f2b(f0[3]);
          h[4]=f2b(f1[0]); h[5]=f2b(f1[1]); h[6]=f2b(f1[2]); h[7]=f2b(f1[3]);
        } else if (j == 1) {
          bf16x8 hx = *(const bf16x8*)(xb + (size_t)v * D + cl * 8);
          #pragma unroll
          for (int k = 0; k < 8; k++) h[k] = f2b((float)hx[k] * cntf);
        } else {
          const float* p = sea + (size_t)v * D + cl * 8;
          f32x4 f0 = *(const f32x4*)p, f1 = *(const f32x4*)(p + 4);
          h[0]=f2b(f0[0]); h[1]=f2b(f0[1]); h[2]=f2b(f0[2]); h[3]=f2b(f0[3]);
          h[4]=f2b(f1[0]); h[5]=f2b(f1[1]); h[6]=f2b(f1[2]); h[7]=f2b(f1[3]);
        }
      } else h = bzero8();
      *(bf16x8*)&lds[m * 392 + c * 8] = h;
    }
  }
  __syncthreads();

  // ---- stage-1 GEMM (K=384)
  f32x4 acc[4][2];
  #pragma unroll
  for (int mt = 0; mt < 4; mt++)
    #pragma unroll
    for (int tt = 0; tt < 2; tt++) acc[mt][tt] = (f32x4){0.f, 0.f, 0.f, 0.f};

  #pragma unroll
  for (int kb = 0; kb < 12; kb++) {
    bf16x8 B0 = *(const bf16x8*)(W1p + ((kb * 8 + wave * 2 + 0) * 64 + lane) * 8);
    bf16x8 B1 = *(const bf16x8*)(W1p + ((kb * 8 + wave * 2 + 1) * 64 + lane) * 8);
    #pragma unroll
    for (int mt = 0; mt < 4; mt++) {
      bf16x8 a = *(const bf16x8*)&lds[(mt * 16 + l16) * 392 + kb * 32 + quad * 8];
      acc[mt][0] = __builtin_amdgcn_mfma_f32_16x16x32_bf16(a, B0, acc[mt][0], 0, 0, 0);
      acc[mt][1] = __builtin_amdgcn_mfma_f32_16x16x32_bf16(a, B1, acc[mt][1], 0, 0, 0);
    }
  }
  __syncthreads();                      // all A1 reads done; lds reused as A2

  // ---- epilogue-1: agg = acc + cnt*b1 -> bf16 into A2 cols [0,128), stride 264
  #pragma unroll
  for (int tt = 0; tt < 2; tt++) {
    int col = wave * 32 + tt * 16 + l16;
    float bb = b1[col];
    #pragma unroll
    for (int mt = 0; mt < 4; mt++)
      #pragma unroll
      for (int r = 0; r < 4; r++) {
        int m = mt * 16 + quad * 4 + r;
        int v = n0 + m;
        float cntf = (v < NN) ? (float)(row_ptr[v + 1] - row_ptr[v]) : 0.f;
        lds[m * 264 + col] = f2b(acc[mt][tt][r] + cntf * bb);
      }
  }
  // ---- A2 cols [128,256) = xb
  #pragma unroll
  for (int i = 0; i < 4; i++) {
    int m = (tid >> 4) + 16 * i;
    int c = tid & 15;
    int v = n0 + m;
    bf16x8 h = (v < NN) ? *(const bf16x8*)(xb + (size_t)v * D + c * 8) : bzero8();
    *(bf16x8*)&lds[m * 264 + 128 + c * 8] = h;
  }
  __syncthreads();

  // ---- stage-2 GEMM (K=256)
  f32x4 acc2[4][2];
  #pragma unroll
  for (int mt = 0; mt < 4; mt++)
    #pragma unroll
    for (int tt = 0; tt < 2; tt++) acc2[mt][tt] = (f32x4){0.f, 0.f, 0.f, 0.f};

  #pragma unroll
  for (int kb = 0; kb < 8; kb++) {
    bf16x8 B0 = *(const bf16x8*)(W2p + ((kb * 8 + wave * 2 + 0) * 64 + lane) * 8);
    bf16x8 B1 = *(const bf16x8*)(W2p + ((kb * 8 + wave * 2 + 1) * 64 + lane) * 8);
    #pragma unroll
    for (int mt = 0; mt < 4; mt++) {
      bf16x8 a = *(const bf16x8*)&lds[(mt * 16 + l16) * 264 + kb * 32 + quad * 8];
      acc2[mt][0] = __builtin_amdgcn_mfma_f32_16x16x32_bf16(a, B0, acc2[mt][0], 0, 0, 0);
      acc2[mt][1] = __builtin_amdgcn_mfma_f32_16x16x32_bf16(a, B1, acc2[mt][1], 0, 0, 0);
    }
  }

  #pragma unroll
  for (int tt = 0; tt < 2; tt++) {
    int col = wave * 32 + tt * 16 + l16;
    float bb = b2[col];
    #pragma unroll
    for (int mt = 0; mt < 4; mt++)
      #pragma unroll
      for (int r = 0; r < 4; r++) {
        int v = n0 + mt * 16 + quad * 4 + r;
        if (v < NN) out[(size_t)v * D + col] = acc2[mt][tt][r] + bb;
      }
  }
}

// ---------------------------------------------------------------------------
extern "C" void kernel_launch(void* const* d_in, const int* in_sizes, int n_in,
                              void* d_out, int out_size, void* d_ws, size_t ws_size,
                              hipStream_t stream) {
  const float* x  = (const float*)d_in[0];
  const int*   ei = (const int*)  d_in[1];   // [2, E]: src = ei, dst = ei + ED
  const float* ea = (const float*)d_in[2];
  const float* W1 = (const float*)d_in[3];
  const float* b1 = (const float*)d_in[4];
  const float* W2 = (const float*)d_in[5];
  const float* b2 = (const float*)d_in[6];
  float* out = (float*)d_out;

  char* ws = (char*)d_ws;
  size_t off = 0;
  auto alloc = [&](size_t bytes) -> void* {
    void* p = ws + off;
    off += (bytes + 255) & ~(size_t)255;
    return p;
  };
  bf16*  xb      = (bf16*)alloc((size_t)NN * D * 2);
  bf16*  W1p     = (bf16*)alloc(49152 * 2);       // 384*128
  bf16*  W2p     = (bf16*)alloc(32768 * 2);       // 256*128
  float* sx      = (float*)alloc((size_t)NN * D * 4);
  float* sea     = (float*)alloc((size_t)NN * D * 4);
  int*   counts  = (int*)alloc(NN * 4);
  int*   row_ptr = (int*)alloc((NN + 1) * 4);
  int*   hist    = (int*)alloc((size_t)NB * NN * 4);   // 2.56 MB block-partials
  int2*  csr     = (int2*)alloc((size_t)ED * 8);
  (void)ws_size; (void)in_sizes; (void)n_in; (void)out_size;  // ~21 MB

  const int* src = ei;
  const int* dst = ei + ED;

  k_prep<<<665, 256, 0, stream>>>(x, W1, W2, xb, W1p, W2p);
  k_hist<<<NB, 256, 0, stream>>>(dst, hist);
  k_colscan<<<40, 256, 0, stream>>>(hist, counts);
  k_scan<<<1, 256, 0, stream>>>(counts, row_ptr);
  k_fill<<<NB, 256, 0, stream>>>(src, dst, row_ptr, hist, csr);
  k_sum<<<2500, 256, 0, stream>>>(xb, ea, row_ptr, csr, sx, sea);
  k_out<<<157, 256, 0, stream>>>(sx, sea, xb, W1p, W2p, b1, b2, row_ptr, out);
}